// Round 1
// 2023.308 us; speedup vs baseline: 1.3035x; 1.3035x over previous
//
#include <hip/hip_runtime.h>
#include <hip/hip_bf16.h>

typedef __bf16 bf16x8 __attribute__((ext_vector_type(8)));
typedef __bf16 bf16x4 __attribute__((ext_vector_type(4)));
typedef float  f32x4  __attribute__((ext_vector_type(4)));

#define TM       64
#define NTHREADS 512
#define XS       392            // X/H row stride (bf16 elems): 384+8 pad -> 784 B, 16B-aligned
#define YS       520            // Y row stride: 512+8 pad -> 1040 B, 16B-aligned
#define SM_H     66560          // after Y region (64*520*2)
#define SM_GATE  116736         // after H region (64*392*2)
#define SM_IDX   116992
#define SM_GATEW 117504         // 384 f32 contiguous copy of W2[:,0]
#define SM_TOTAL 119040

// ws layout (bf16 elems): W1t[384][384] | W2t[512][384] (cols 1..512 of W2) | W3t[128][512]
#define W1T_ELEMS 147456
#define W2T_ELEMS 196608
#define W3T_ELEMS 65536

#define MFMA(w, a, c) __builtin_amdgcn_mfma_f32_16x16x32_bf16((w), (a), (c), 0, 0, 0)

__global__ void prep_weights(const float* __restrict__ W1, const float* __restrict__ W2,
                             const float* __restrict__ W3, __bf16* __restrict__ ws) {
    int i = blockIdx.x * blockDim.x + threadIdx.x;   // 800*512 = 409600 exact
    if (i < W1T_ELEMS) {
        int n = i / 384, k = i - n * 384;
        ws[i] = (__bf16)W1[k * 384 + n];
    } else if (i < W1T_ELEMS + W2T_ELEMS) {
        int j = i - W1T_ELEMS;
        int n = j / 384, k = j - n * 384;
        ws[i] = (__bf16)W2[k * 513 + n + 1];         // skip gate column 0
    } else {
        int j = i - (W1T_ELEMS + W2T_ELEMS);
        int n = j / 512, k = j - n * 512;
        ws[i] = (__bf16)W3[k * 128 + n];
    }
}

__global__ __launch_bounds__(NTHREADS, 2) void fused_edge_mlp(
    const float* __restrict__ vc, const float* __restrict__ ve1, const float* __restrict__ ve2,
    const int* __restrict__ src, const int* __restrict__ dst,
    const float* __restrict__ b1, const float* __restrict__ W2, const float* __restrict__ b2,
    const float* __restrict__ b3,
    const __bf16* __restrict__ W1t, const __bf16* __restrict__ W2t, const __bf16* __restrict__ W3t,
    float* __restrict__ out)
{
    extern __shared__ char smem[];
    __bf16* sX    = (__bf16*)smem;               // [64][392], dead after phase A
    __bf16* sY    = (__bf16*)smem;               // [64][520], overlays X
    __bf16* sH    = (__bf16*)(smem + SM_H);      // [64][392]
    float*  sGate = (float*)(smem + SM_GATE);    // [64]
    int*    sIdx  = (int*)(smem + SM_IDX);       // [128]
    float*  sGateW= (float*)(smem + SM_GATEW);   // [384] contiguous W2[:,0]

    const int tid  = threadIdx.x;
    const int wave = tid >> 6;
    const int lane = tid & 63;
    const int quad = lane >> 4;
    const int l16  = lane & 15;
    const int e0   = blockIdx.x * TM;

    if (tid < TM) {
        sIdx[tid]      = src[e0 + tid];
        sIdx[TM + tid] = dst[e0 + tid];
    }
    if (tid < 384) sGateW[tid] = W2[tid * 513];   // one-time strided read, overlapped
    __syncthreads();

    // ---- gather: issue all 12 loads into regs, then convert+store ----
    float4 g[12];
    #pragma unroll
    for (int it = 0; it < 12; ++it) {
        const int q = tid + it * NTHREADS;
        const int row = q / 96, seg = q - row * 96;
        const float4* p;
        if (seg < 64) {
            p = (const float4*)(vc + (size_t)sIdx[(seg >> 5) * TM + row] * 128) + (seg & 31);
        } else {
            const float* b = (seg < 80) ? ve1 : ve2;
            p = (const float4*)(b + (size_t)(e0 + row) * 64) + ((seg - 64) & 15);
        }
        g[it] = *p;
    }

    // ---- issue phase-A weight prefetch (kt=0,1) before the barrier ----
    bf16x8 wa[3], wb[3];
    {
        const int nbase = wave * 48;
        const __bf16* wp = W1t + (size_t)(nbase + l16) * 384 + quad * 8;
        #pragma unroll
        for (int nt = 0; nt < 3; ++nt) {
            wa[nt] = *(const bf16x8*)(wp + nt * 16 * 384);
            wb[nt] = *(const bf16x8*)(wp + nt * 16 * 384 + 32);
        }
    }

    #pragma unroll
    for (int it = 0; it < 12; ++it) {
        const int q = tid + it * NTHREADS;
        const int row = q / 96, seg = q - row * 96;
        bf16x4 t = { (__bf16)g[it].x, (__bf16)g[it].y, (__bf16)g[it].z, (__bf16)g[it].w };
        *(bf16x4*)(sX + row * XS + seg * 4) = t;
    }
    __syncthreads();

    // ---- phase A: H = relu(X @ W1 + b1), swapped operands, depth-2 W prefetch ----
    {
        const int nbase = wave * 48;
        const __bf16* wp = W1t + (size_t)(nbase + l16) * 384 + quad * 8;
        f32x4 acc[3][4] = {};
        #pragma unroll
        for (int kt = 0; kt < 12; kt += 2) {
            {
                const int k0 = kt * 32 + quad * 8;
                bf16x8 a0 = *(const bf16x8*)(sX + (0 * 16 + l16) * XS + k0);
                bf16x8 a1 = *(const bf16x8*)(sX + (1 * 16 + l16) * XS + k0);
                bf16x8 a2 = *(const bf16x8*)(sX + (2 * 16 + l16) * XS + k0);
                bf16x8 a3 = *(const bf16x8*)(sX + (3 * 16 + l16) * XS + k0);
                #pragma unroll
                for (int nt = 0; nt < 3; ++nt) {
                    acc[nt][0] = MFMA(wa[nt], a0, acc[nt][0]);
                    acc[nt][1] = MFMA(wa[nt], a1, acc[nt][1]);
                    acc[nt][2] = MFMA(wa[nt], a2, acc[nt][2]);
                    acc[nt][3] = MFMA(wa[nt], a3, acc[nt][3]);
                }
                if (kt + 2 < 12) {
                    #pragma unroll
                    for (int nt = 0; nt < 3; ++nt)
                        wa[nt] = *(const bf16x8*)(wp + nt * 16 * 384 + (kt + 2) * 32);
                }
            }
            {
                const int k1 = (kt + 1) * 32 + quad * 8;
                bf16x8 a0 = *(const bf16x8*)(sX + (0 * 16 + l16) * XS + k1);
                bf16x8 a1 = *(const bf16x8*)(sX + (1 * 16 + l16) * XS + k1);
                bf16x8 a2 = *(const bf16x8*)(sX + (2 * 16 + l16) * XS + k1);
                bf16x8 a3 = *(const bf16x8*)(sX + (3 * 16 + l16) * XS + k1);
                #pragma unroll
                for (int nt = 0; nt < 3; ++nt) {
                    acc[nt][0] = MFMA(wb[nt], a0, acc[nt][0]);
                    acc[nt][1] = MFMA(wb[nt], a1, acc[nt][1]);
                    acc[nt][2] = MFMA(wb[nt], a2, acc[nt][2]);
                    acc[nt][3] = MFMA(wb[nt], a3, acc[nt][3]);
                }
                if (kt + 3 < 12) {
                    #pragma unroll
                    for (int nt = 0; nt < 3; ++nt)
                        wb[nt] = *(const bf16x8*)(wp + nt * 16 * 384 + (kt + 3) * 32);
                }
            }
        }
        // epilogue: lane = m (l16), regs = 4 consecutive n -> packed bf16x4 stores
        #pragma unroll
        for (int nt = 0; nt < 3; ++nt) {
            const int nb = nbase + nt * 16 + quad * 4;
            const float4 bi = *(const float4*)(b1 + nb);
            #pragma unroll
            for (int mt = 0; mt < 4; ++mt) {
                f32x4 v = acc[nt][mt];
                float x0 = v[0] + bi.x, x1 = v[1] + bi.y, x2 = v[2] + bi.z, x3 = v[3] + bi.w;
                bf16x4 t = { (__bf16)(x0 > 0.f ? x0 : 0.f), (__bf16)(x1 > 0.f ? x1 : 0.f),
                             (__bf16)(x2 > 0.f ? x2 : 0.f), (__bf16)(x3 > 0.f ? x3 : 0.f) };
                *(bf16x4*)(sH + (mt * 16 + l16) * XS + nb) = t;
            }
        }
    }

    // ---- issue phase-B weight prefetch (kt=0,1) before the barrier ----
    bf16x8 vwa[4], vwb[4];
    {
        const __bf16* wp = W2t + (size_t)(wave * 64 + l16) * 384 + quad * 8;
        #pragma unroll
        for (int nt = 0; nt < 4; ++nt) {
            vwa[nt] = *(const bf16x8*)(wp + nt * 16 * 384);
            vwb[nt] = *(const bf16x8*)(wp + nt * 16 * 384 + 32);
        }
    }
    __syncthreads();

    // ---- gate: y0 = H . W2[:,0] + b2[0]; sigmoid. 8 threads per row, LDS weights ----
    {
        const int row = tid >> 3, part = tid & 7;
        const __bf16* hp = sH + row * XS + part * 48;
        const float*  gw = sGateW + part * 48;
        float s0 = 0.f, s1 = 0.f;
        #pragma unroll
        for (int kb = 0; kb < 6; ++kb) {
            bf16x8 h = *(const bf16x8*)(hp + kb * 8);
            #pragma unroll
            for (int j = 0; j < 4; ++j) {
                s0 += (float)h[j]     * gw[kb * 8 + j];
                s1 += (float)h[j + 4] * gw[kb * 8 + j + 4];
            }
        }
        float s = s0 + s1;
        s += __shfl_down(s, 4, 8);
        s += __shfl_down(s, 2, 8);
        s += __shfl_down(s, 1, 8);
        if (part == 0) sGate[row] = 1.f / (1.f + __expf(-(s + b2[0])));
    }

    // ---- phase B: Ytail = H @ W2[:,1:] + b2[1:], swapped, depth-2 prefetch ----
    {
        const __bf16* wp = W2t + (size_t)(wave * 64 + l16) * 384 + quad * 8;
        f32x4 acc[4][4] = {};
        #pragma unroll
        for (int kt = 0; kt < 12; kt += 2) {
            {
                const int k0 = kt * 32 + quad * 8;
                bf16x8 a0 = *(const bf16x8*)(sH + (0 * 16 + l16) * XS + k0);
                bf16x8 a1 = *(const bf16x8*)(sH + (1 * 16 + l16) * XS + k0);
                bf16x8 a2 = *(const bf16x8*)(sH + (2 * 16 + l16) * XS + k0);
                bf16x8 a3 = *(const bf16x8*)(sH + (3 * 16 + l16) * XS + k0);
                #pragma unroll
                for (int nt = 0; nt < 4; ++nt) {
                    acc[nt][0] = MFMA(vwa[nt], a0, acc[nt][0]);
                    acc[nt][1] = MFMA(vwa[nt], a1, acc[nt][1]);
                    acc[nt][2] = MFMA(vwa[nt], a2, acc[nt][2]);
                    acc[nt][3] = MFMA(vwa[nt], a3, acc[nt][3]);
                }
                if (kt + 2 < 12) {
                    #pragma unroll
                    for (int nt = 0; nt < 4; ++nt)
                        vwa[nt] = *(const bf16x8*)(wp + nt * 16 * 384 + (kt + 2) * 32);
                }
            }
            {
                const int k1 = (kt + 1) * 32 + quad * 8;
                bf16x8 a0 = *(const bf16x8*)(sH + (0 * 16 + l16) * XS + k1);
                bf16x8 a1 = *(const bf16x8*)(sH + (1 * 16 + l16) * XS + k1);
                bf16x8 a2 = *(const bf16x8*)(sH + (2 * 16 + l16) * XS + k1);
                bf16x8 a3 = *(const bf16x8*)(sH + (3 * 16 + l16) * XS + k1);
                #pragma unroll
                for (int nt = 0; nt < 4; ++nt) {
                    acc[nt][0] = MFMA(vwb[nt], a0, acc[nt][0]);
                    acc[nt][1] = MFMA(vwb[nt], a1, acc[nt][1]);
                    acc[nt][2] = MFMA(vwb[nt], a2, acc[nt][2]);
                    acc[nt][3] = MFMA(vwb[nt], a3, acc[nt][3]);
                }
                if (kt + 3 < 12) {
                    #pragma unroll
                    for (int nt = 0; nt < 4; ++nt)
                        vwb[nt] = *(const bf16x8*)(wp + nt * 16 * 384 + (kt + 3) * 32);
                }
            }
        }
        // epilogue: packed bf16x4 stores along n
        #pragma unroll
        for (int nt = 0; nt < 4; ++nt) {
            const int col = (wave * 4 + nt) * 16 + quad * 4;       // y column = col+1
            const float bx = b2[col + 1], by = b2[col + 2], bz = b2[col + 3], bw = b2[col + 4];
            #pragma unroll
            for (int mt = 0; mt < 4; ++mt) {
                f32x4 v = acc[nt][mt];
                bf16x4 t = { (__bf16)(v[0] + bx), (__bf16)(v[1] + by),
                             (__bf16)(v[2] + bz), (__bf16)(v[3] + bw) };
                *(bf16x4*)(sY + (mt * 16 + l16) * YS + col) = t;
            }
        }
    }

    // ---- issue phase-C weight prefetch (kt=0,1) before the barrier ----
    const __bf16* w3p = W3t + (size_t)(wave * 16 + l16) * 512 + quad * 8;
    bf16x8 cwa = *(const bf16x8*)(w3p);
    bf16x8 cwb = *(const bf16x8*)(w3p + 32);
    __syncthreads();

    // ---- phase C: out = gate * (Ytail @ W3) + b3, swapped, depth-2 prefetch ----
    {
        f32x4 acc[4] = {};
        #pragma unroll
        for (int kt = 0; kt < 16; kt += 2) {
            {
                const int k0 = kt * 32 + quad * 8;
                bf16x8 a0 = *(const bf16x8*)(sY + (0 * 16 + l16) * YS + k0);
                bf16x8 a1 = *(const bf16x8*)(sY + (1 * 16 + l16) * YS + k0);
                bf16x8 a2 = *(const bf16x8*)(sY + (2 * 16 + l16) * YS + k0);
                bf16x8 a3 = *(const bf16x8*)(sY + (3 * 16 + l16) * YS + k0);
                acc[0] = MFMA(cwa, a0, acc[0]);
                acc[1] = MFMA(cwa, a1, acc[1]);
                acc[2] = MFMA(cwa, a2, acc[2]);
                acc[3] = MFMA(cwa, a3, acc[3]);
                if (kt + 2 < 16) cwa = *(const bf16x8*)(w3p + (kt + 2) * 32);
            }
            {
                const int k1 = (kt + 1) * 32 + quad * 8;
                bf16x8 a0 = *(const bf16x8*)(sY + (0 * 16 + l16) * YS + k1);
                bf16x8 a1 = *(const bf16x8*)(sY + (1 * 16 + l16) * YS + k1);
                bf16x8 a2 = *(const bf16x8*)(sY + (2 * 16 + l16) * YS + k1);
                bf16x8 a3 = *(const bf16x8*)(sY + (3 * 16 + l16) * YS + k1);
                acc[0] = MFMA(cwb, a0, acc[0]);
                acc[1] = MFMA(cwb, a1, acc[1]);
                acc[2] = MFMA(cwb, a2, acc[2]);
                acc[3] = MFMA(cwb, a3, acc[3]);
                if (kt + 3 < 16) cwb = *(const bf16x8*)(w3p + (kt + 3) * 32);
            }
        }
        const int colb = wave * 16 + quad * 4;
        const float4 b3v = *(const float4*)(b3 + colb);
        #pragma unroll
        for (int mt = 0; mt < 4; ++mt) {
            const int row = mt * 16 + l16;
            const float gte = sGate[row];
            float4 o = { acc[mt][0] * gte + b3v.x, acc[mt][1] * gte + b3v.y,
                         acc[mt][2] * gte + b3v.z, acc[mt][3] * gte + b3v.w };
            *(float4*)(out + (size_t)(e0 + row) * 128 + colb) = o;
        }
    }
}

extern "C" void kernel_launch(void* const* d_in, const int* in_sizes, int n_in,
                              void* d_out, int out_size, void* d_ws, size_t ws_size,
                              hipStream_t stream) {
    const float* vc  = (const float*)d_in[0];
    const float* ve1 = (const float*)d_in[1];
    const float* ve2 = (const float*)d_in[2];
    const int*   src = (const int*)d_in[3];
    const int*   dst = (const int*)d_in[4];
    const float* W1  = (const float*)d_in[5];
    const float* b1  = (const float*)d_in[6];
    const float* W2  = (const float*)d_in[7];
    const float* b2  = (const float*)d_in[8];
    const float* W3  = (const float*)d_in[9];
    const float* b3  = (const float*)d_in[10];
    float* out = (float*)d_out;

    __bf16* W1t = (__bf16*)d_ws;
    __bf16* W2t = W1t + W1T_ELEMS;
    __bf16* W3t = W2t + W2T_ELEMS;

    prep_weights<<<800, 512, 0, stream>>>(W1, W2, W3, W1t);

    hipFuncSetAttribute((const void*)fused_edge_mlp,
                        hipFuncAttributeMaxDynamicSharedMemorySize, SM_TOTAL);
    fused_edge_mlp<<<12500, NTHREADS, SM_TOTAL, stream>>>(
        vc, ve1, ve2, src, dst, b1, W2, b2, b3, W1t, W2t, W3t, out);
}